// Round 6
// baseline (85.980 us; speedup 1.0000x reference)
//
#include <hip/hip_runtime.h>
#include <hip/hip_bf16.h>

typedef __attribute__((ext_vector_type(8))) short bf16x8;
typedef __attribute__((ext_vector_type(4))) float f32x4;
typedef __attribute__((ext_vector_type(4))) unsigned short u16x4;

static constexpr int D = 256;
static constexpr float INV_T = 2.0f;                 // 1 / temperature(0.5)
static constexpr float KEXP2 = 2.8853900817779268f;  // 2 * log2(e): exp(2x) = 2^(KEXP2*x)
static constexpr int BM = 128;                       // tile side
static constexpr int BK = 64;                        // K-slice
static constexpr int NKS = D / BK;                   // 4 K-steps
static constexpr int TTILE = 64;                     // 8192 / 128
static constexpr int NBLK = TTILE * (TTILE + 1) / 2; // 2080 upper-triangle tiles

__device__ inline unsigned short f2bf(float x) {
    unsigned int u = __builtin_bit_cast(unsigned int, x);
    u += 0x7fffu + ((u >> 16) & 1u);   // round-to-nearest-even
    return (unsigned short)(u >> 16);
}
__device__ inline float bf2f(unsigned short h) {
    unsigned int u = ((unsigned int)h) << 16;
    return __builtin_bit_cast(float, u);
}
__device__ inline float fexp2(float x) {
#if __has_builtin(__builtin_amdgcn_exp2f)
    return __builtin_amdgcn_exp2f(x);
#else
    return exp2f(x);
#endif
}

// Kernel 1: per pair i in [0,B): normalize rows i and i+B to bf16,
// rowsum init = -exp(2*selfdot) (diagonal removal), positive-pair dot ->
// per-block partial (no global atomics).
__global__ void k_norm(const float* __restrict__ zi, const float* __restrict__ zj,
                       unsigned short* __restrict__ zn, float* __restrict__ rowsum,
                       float* __restrict__ pos_partial, int B) {
    __shared__ float red[4];
    const int lane = threadIdx.x & 63;
    const int wv = threadIdx.x >> 6;
    const int i = blockIdx.x * 4 + wv;       // pair index
    if (i < B) {
        float4 vi = reinterpret_cast<const float4*>(zi + (size_t)i * D)[lane];
        float4 vj = reinterpret_cast<const float4*>(zj + (size_t)i * D)[lane];
        float ssi = vi.x * vi.x + vi.y * vi.y + vi.z * vi.z + vi.w * vi.w;
        float ssj = vj.x * vj.x + vj.y * vj.y + vj.z * vj.z + vj.w * vj.w;
#pragma unroll
        for (int off = 32; off >= 1; off >>= 1) {
            ssi += __shfl_xor(ssi, off, 64);
            ssj += __shfl_xor(ssj, off, 64);
        }
        float rni = rsqrtf(ssi), rnj = rsqrtf(ssj);
        unsigned short a0 = f2bf(vi.x * rni), a1 = f2bf(vi.y * rni);
        unsigned short a2 = f2bf(vi.z * rni), a3 = f2bf(vi.w * rni);
        unsigned short b0 = f2bf(vj.x * rnj), b1 = f2bf(vj.y * rnj);
        unsigned short b2 = f2bf(vj.z * rnj), b3 = f2bf(vj.w * rnj);
        u16x4 oa; oa.x = a0; oa.y = a1; oa.z = a2; oa.w = a3;
        u16x4 ob; ob.x = b0; ob.y = b1; ob.z = b2; ob.w = b3;
        *reinterpret_cast<u16x4*>(zn + (size_t)i * D + lane * 4) = oa;
        *reinterpret_cast<u16x4*>(zn + (size_t)(i + B) * D + lane * 4) = ob;
        // self-dots + pair-dot with bf16-rounded values (match MFMA closely)
        float fa0 = bf2f(a0), fa1 = bf2f(a1), fa2 = bf2f(a2), fa3 = bf2f(a3);
        float fb0 = bf2f(b0), fb1 = bf2f(b1), fb2 = bf2f(b2), fb3 = bf2f(b3);
        float sdi = fa0 * fa0 + fa1 * fa1 + fa2 * fa2 + fa3 * fa3;
        float sdj = fb0 * fb0 + fb1 * fb1 + fb2 * fb2 + fb3 * fb3;
        float pd  = fa0 * fb0 + fa1 * fb1 + fa2 * fb2 + fa3 * fb3;
#pragma unroll
        for (int off = 32; off >= 1; off >>= 1) {
            sdi += __shfl_xor(sdi, off, 64);
            sdj += __shfl_xor(sdj, off, 64);
            pd  += __shfl_xor(pd, off, 64);
        }
        if (lane == 0) {
            rowsum[i]     = -fexp2(KEXP2 * sdi);
            rowsum[i + B] = -fexp2(KEXP2 * sdj);
            red[wv] = pd;
        }
    } else if (lane == 0) {
        red[wv] = 0.f;
    }
    __syncthreads();
    if (threadIdx.x == 0)
        pos_partial[blockIdx.x] = 2.0f * INV_T * (red[0] + red[1] + red[2] + red[3]);
}

// Kernel 2: upper-triangle 128x128 sim tiles. 4 waves (2x2), wave owns 64x64
// (acc = 64 VGPRs). A and B K-slices (BK=64) staged in LDS in MFMA-fragment
// order, double-buffered = 64 KB exactly -> 2 blocks/CU (the R5 failure was
// 1 block/CU: every barrier drain fully exposed). ~180 VGPRs, no spill.
__global__ __launch_bounds__(256, 2)
void k_main(const unsigned short* __restrict__ zn, float* __restrict__ rowsum, int N) {
    // [buf][panel A=0/B=1][frag f=rf*2+kk][lane][8 bf16] = 64 KB
    __shared__ __align__(16) unsigned short lds[2][2][16][64][8];
    const int tid = threadIdx.x;
    const int lane = tid & 63, wv = tid >> 6;
    const int l15 = lane & 15, lhi = lane >> 4;
    const int wr = wv >> 1, wc = wv & 1;         // wave grid 2 x 2

    // decode upper-triangle tile (ti <= tj)
    int ti = 0, rem = blockIdx.x;
    while (rem >= TTILE - ti) { rem -= TTILE - ti; ++ti; }
    const int tj = ti + rem;
    const bool is_diag = (ti == tj);
    const int i0 = ti * BM, j0 = tj * BM;

    // staging: thread's chunk j (j=0..3) -> frag f = wv + 4*j; rf = f>>1, kk = f&1
    // panel element: row = rf*16 + l15, k-in-slice = kk*32 + lhi*8
    int srow[4], scol[4];
#pragma unroll
    for (int j = 0; j < 4; ++j) {
        int f = wv + 4 * j;
        srow[j] = (f >> 1) * 16 + l15;
        scol[j] = (f & 1) * 32 + lhi * 8;
    }

    bf16x8* ldsv = reinterpret_cast<bf16x8*>(lds);

    f32x4 acc[4][4];
#pragma unroll
    for (int r = 0; r < 4; ++r)
#pragma unroll
        for (int c = 0; c < 4; ++c) acc[r][c] = (f32x4){0.f, 0.f, 0.f, 0.f};

    bf16x8 sa[4], sb[4];
    // prologue: stage K-slice 0 into buffer 0 (linear conflict-free writes)
#pragma unroll
    for (int j = 0; j < 4; ++j) {
        sa[j] = *reinterpret_cast<const bf16x8*>(zn + (size_t)(i0 + srow[j]) * D + scol[j]);
        sb[j] = *reinterpret_cast<const bf16x8*>(zn + (size_t)(j0 + srow[j]) * D + scol[j]);
    }
#pragma unroll
    for (int j = 0; j < 4; ++j) {
        ldsv[tid + 256 * j] = sa[j];
        ldsv[1024 + tid + 256 * j] = sb[j];
    }
    __syncthreads();

    for (int ks = 0; ks < NKS; ++ks) {
        const int buf = ks & 1;
        if (ks + 1 < NKS) {   // T14: issue next slice's global loads early
            const int kb = (ks + 1) * BK;
#pragma unroll
            for (int j = 0; j < 4; ++j) {
                sa[j] = *reinterpret_cast<const bf16x8*>(zn + (size_t)(i0 + srow[j]) * D + kb + scol[j]);
                sb[j] = *reinterpret_cast<const bf16x8*>(zn + (size_t)(j0 + srow[j]) * D + kb + scol[j]);
            }
        }
        const bf16x8* base = ldsv + buf * 2048;
#pragma unroll
        for (int kk = 0; kk < 2; ++kk) {
            bf16x8 af[4], bfr[4];
#pragma unroll
            for (int r = 0; r < 4; ++r)
                af[r] = base[((wr * 4 + r) * 2 + kk) * 64 + lane];
#pragma unroll
            for (int c = 0; c < 4; ++c)
                bfr[c] = base[1024 + ((wc * 4 + c) * 2 + kk) * 64 + lane];
#pragma unroll
            for (int r = 0; r < 4; ++r)
#pragma unroll
                for (int c = 0; c < 4; ++c)
                    acc[r][c] = __builtin_amdgcn_mfma_f32_16x16x32_bf16(af[r], bfr[c], acc[r][c], 0, 0, 0);
        }
        if (ks + 1 < NKS) {   // write next slice into the other buffer (linear)
#pragma unroll
            for (int j = 0; j < 4; ++j) {
                ldsv[(buf ^ 1) * 2048 + tid + 256 * j] = sa[j];
                ldsv[(buf ^ 1) * 2048 + 1024 + tid + 256 * j] = sb[j];
            }
        }
        __syncthreads();
    }

    // tail: e = exp(2*sim); row-sums always, col-sums for off-diagonal tiles.
    // D-frag mapping: col = wc*64 + c*16 + l15, row = wr*64 + r*16 + lhi*4 + q
    float cs[4] = {0.f, 0.f, 0.f, 0.f};
#pragma unroll
    for (int r = 0; r < 4; ++r) {
        float rsq[4] = {0.f, 0.f, 0.f, 0.f};
#pragma unroll
        for (int c = 0; c < 4; ++c)
#pragma unroll
            for (int q = 0; q < 4; ++q) {
                float e = fexp2(KEXP2 * acc[r][c][q]);
                rsq[q] += e;
                cs[c] += e;
            }
#pragma unroll
        for (int q = 0; q < 4; ++q) {
            float v = rsq[q];
            v += __shfl_xor(v, 1, 64);
            v += __shfl_xor(v, 2, 64);
            v += __shfl_xor(v, 4, 64);
            v += __shfl_xor(v, 8, 64);
            if (l15 == 0)
                atomicAdd(&rowsum[i0 + wr * 64 + r * 16 + lhi * 4 + q], v);
        }
    }
    if (!is_diag) {
#pragma unroll
        for (int c = 0; c < 4; ++c) {
            float v = cs[c];
            v += __shfl_xor(v, 16, 64);
            v += __shfl_xor(v, 32, 64);
            if (lhi == 0)
                atomicAdd(&rowsum[j0 + wc * 64 + c * 16 + l15], v);
        }
    }
}

// Kernel 3: loss = (sum_i log(rowsum_i) - sum_b pos_partial_b) / N
__global__ void k_final(const float* __restrict__ rowsum, const float* __restrict__ pos_partial,
                        int n_partial, float* __restrict__ out, int N) {
    __shared__ float red[16];
    int lane = threadIdx.x & 63, wv = threadIdx.x >> 6;
    float local = 0.f;
    for (int i = threadIdx.x; i < N; i += 1024) local += __logf(rowsum[i]);
    for (int i = threadIdx.x; i < n_partial; i += 1024) local -= pos_partial[i];
#pragma unroll
    for (int off = 32; off >= 1; off >>= 1) local += __shfl_xor(local, off, 64);
    if (lane == 0) red[wv] = local;
    __syncthreads();
    if (threadIdx.x == 0) {
        float t = 0.f;
#pragma unroll
        for (int w = 0; w < 16; ++w) t += red[w];
        out[0] = t / (float)N;
    }
}

extern "C" void kernel_launch(void* const* d_in, const int* in_sizes, int n_in,
                              void* d_out, int out_size, void* d_ws, size_t ws_size,
                              hipStream_t stream) {
    const float* zi = (const float*)d_in[0];
    const float* zj = (const float*)d_in[1];
    const int B = in_sizes[0] / D;   // 4096
    const int N = 2 * B;             // 8192

    unsigned short* zn = (unsigned short*)d_ws;                       // N*D bf16 = 4 MB
    float* rowsum = (float*)((char*)d_ws + (size_t)N * D * 2);        // N floats
    float* pos_partial = rowsum + N;                                  // B/4 floats

    float* out = (float*)d_out;

    const int npb = B / 4;  // k_norm blocks == pos partials
    hipLaunchKernelGGL(k_norm, dim3(npb), dim3(256), 0, stream, zi, zj, zn, rowsum, pos_partial, B);
    hipLaunchKernelGGL(k_main, dim3(NBLK), dim3(256), 0, stream, zn, rowsum, N);
    hipLaunchKernelGGL(k_final, dim3(1), dim3(1024), 0, stream, rowsum, pos_partial, npb, out, N);
}

// Round 8
// 84.056 us; speedup vs baseline: 1.0229x; 1.0229x over previous
//
#include <hip/hip_runtime.h>
#include <hip/hip_bf16.h>

typedef __attribute__((ext_vector_type(8))) short bf16x8;
typedef __attribute__((ext_vector_type(4))) float f32x4;
typedef __attribute__((ext_vector_type(4))) unsigned short u16x4;

static constexpr int D = 256;
static constexpr float INV_T = 2.0f;                 // 1 / temperature(0.5)
static constexpr float KEXP2 = 2.8853900817779268f;  // 2 * log2(e): exp(2x) = 2^(KEXP2*x)
static constexpr int BM = 128;                       // tile side
static constexpr int BK = 64;                        // K-slice
static constexpr int NKS = D / BK;                   // 4 K-steps
static constexpr int TTILE = 64;                     // 8192 / 128
static constexpr int NBLK = TTILE * (TTILE + 1) / 2; // 2080 upper-triangle tiles

__device__ inline unsigned short f2bf(float x) {
    unsigned int u = __builtin_bit_cast(unsigned int, x);
    u += 0x7fffu + ((u >> 16) & 1u);   // round-to-nearest-even
    return (unsigned short)(u >> 16);
}
__device__ inline float bf2f(unsigned short h) {
    unsigned int u = ((unsigned int)h) << 16;
    return __builtin_bit_cast(float, u);
}
__device__ inline float fexp2(float x) {
#if __has_builtin(__builtin_amdgcn_exp2f)
    return __builtin_amdgcn_exp2f(x);
#else
    return exp2f(x);
#endif
}
// Direct global->LDS DMA (16B/lane). LDS dest = wave-uniform base + lane*16.
__device__ inline void gload_lds16(const unsigned short* g, unsigned short* l) {
    typedef __attribute__((address_space(3))) unsigned int lds_u32_t;
    typedef __attribute__((address_space(1))) const unsigned int glb_u32_t;
    __builtin_amdgcn_global_load_lds((glb_u32_t*)g, (lds_u32_t*)l, 16, 0, 0);
}

// Kernel 1: per pair i in [0,B): normalize rows i and i+B to bf16,
// diag[i] = -exp(2*selfdot) (diagonal removal term), positive-pair dot ->
// per-block partial (no global atomics).
__global__ void k_norm(const float* __restrict__ zi, const float* __restrict__ zj,
                       unsigned short* __restrict__ zn, float* __restrict__ diag,
                       float* __restrict__ pos_partial, int B) {
    __shared__ float red[4];
    const int lane = threadIdx.x & 63;
    const int wv = threadIdx.x >> 6;
    const int i = blockIdx.x * 4 + wv;       // pair index
    if (i < B) {
        float4 vi = reinterpret_cast<const float4*>(zi + (size_t)i * D)[lane];
        float4 vj = reinterpret_cast<const float4*>(zj + (size_t)i * D)[lane];
        float ssi = vi.x * vi.x + vi.y * vi.y + vi.z * vi.z + vi.w * vi.w;
        float ssj = vj.x * vj.x + vj.y * vj.y + vj.z * vj.z + vj.w * vj.w;
#pragma unroll
        for (int off = 32; off >= 1; off >>= 1) {
            ssi += __shfl_xor(ssi, off, 64);
            ssj += __shfl_xor(ssj, off, 64);
        }
        float rni = rsqrtf(ssi), rnj = rsqrtf(ssj);
        unsigned short a0 = f2bf(vi.x * rni), a1 = f2bf(vi.y * rni);
        unsigned short a2 = f2bf(vi.z * rni), a3 = f2bf(vi.w * rni);
        unsigned short b0 = f2bf(vj.x * rnj), b1 = f2bf(vj.y * rnj);
        unsigned short b2 = f2bf(vj.z * rnj), b3 = f2bf(vj.w * rnj);
        u16x4 oa; oa.x = a0; oa.y = a1; oa.z = a2; oa.w = a3;
        u16x4 ob; ob.x = b0; ob.y = b1; ob.z = b2; ob.w = b3;
        *reinterpret_cast<u16x4*>(zn + (size_t)i * D + lane * 4) = oa;
        *reinterpret_cast<u16x4*>(zn + (size_t)(i + B) * D + lane * 4) = ob;
        // self-dots + pair-dot with bf16-rounded values (match MFMA closely)
        float fa0 = bf2f(a0), fa1 = bf2f(a1), fa2 = bf2f(a2), fa3 = bf2f(a3);
        float fb0 = bf2f(b0), fb1 = bf2f(b1), fb2 = bf2f(b2), fb3 = bf2f(b3);
        float sdi = fa0 * fa0 + fa1 * fa1 + fa2 * fa2 + fa3 * fa3;
        float sdj = fb0 * fb0 + fb1 * fb1 + fb2 * fb2 + fb3 * fb3;
        float pd  = fa0 * fb0 + fa1 * fb1 + fa2 * fb2 + fa3 * fb3;
#pragma unroll
        for (int off = 32; off >= 1; off >>= 1) {
            sdi += __shfl_xor(sdi, off, 64);
            sdj += __shfl_xor(sdj, off, 64);
            pd  += __shfl_xor(pd, off, 64);
        }
        if (lane == 0) {
            diag[i]     = -fexp2(KEXP2 * sdi);
            diag[i + B] = -fexp2(KEXP2 * sdj);
            red[wv] = pd;
        }
    } else if (lane == 0) {
        red[wv] = 0.f;
    }
    __syncthreads();
    if (threadIdx.x == 0)
        pos_partial[blockIdx.x] = 2.0f * INV_T * (red[0] + red[1] + red[2] + red[3]);
}

// Kernel 2: upper-triangle 128x128 sim tiles. 4 waves (2x2), wave owns 64x64.
// A/B K-slices staged via global_load_lds (no staging VGPRs). Row/col partial
// sums are cross-wave combined in LDS (R7 bug: the two wc-waves sharing a row
// both plain-stored to the same P slot -> lost exactly half the sum = ln2
// error), then written NON-atomically to P[64][N] with exactly-once coverage.
__global__ __launch_bounds__(256, 2)
void k_main(const unsigned short* __restrict__ zn, float* __restrict__ P, int N) {
    // [buf][panel A=0/B=1][frag f][lane][8 bf16] = 64 KB
    __shared__ __align__(16) unsigned short lds[2][2][16][64][8];
    const int tid = threadIdx.x;
    const int lane = tid & 63, wv = tid >> 6;
    const int l15 = lane & 15, lhi = lane >> 4;
    const int wr = wv >> 1, wc = wv & 1;         // wave grid 2 x 2

    // decode upper-triangle tile (ti <= tj)
    int ti = 0, rem = blockIdx.x;
    while (rem >= TTILE - ti) { rem -= TTILE - ti; ++ti; }
    const int tj = ti + rem;
    const bool is_diag = (ti == tj);
    const int i0 = ti * BM, j0 = tj * BM;

    // staging chunk j -> fragment f = wv + 4*j (wave-uniform LDS base);
    // global source: row = (f>>1)*16 + l15, k-in-slice = (f&1)*32 + lhi*8.
    const unsigned short* ga[4];
    const unsigned short* gb[4];
    unsigned short* const ldsbase = &lds[0][0][0][0][0];
#pragma unroll
    for (int j = 0; j < 4; ++j) {
        int f = wv + 4 * j;
        int srow = (f >> 1) * 16 + l15;
        int scol = (f & 1) * 32 + lhi * 8;
        ga[j] = zn + (size_t)(i0 + srow) * D + scol;
        gb[j] = zn + (size_t)(j0 + srow) * D + scol;
    }

    bf16x8* ldsv = reinterpret_cast<bf16x8*>(ldsbase);

    f32x4 acc[4][4];
#pragma unroll
    for (int r = 0; r < 4; ++r)
#pragma unroll
        for (int c = 0; c < 4; ++c) acc[r][c] = (f32x4){0.f, 0.f, 0.f, 0.f};

#define STAGE(bufv, ksv)                                                        \
    do {                                                                        \
        const int koff_ = (ksv) * BK;                                           \
        _Pragma("unroll")                                                       \
        for (int j_ = 0; j_ < 4; ++j_) {                                        \
            int f_ = wv + 4 * j_;                                               \
            gload_lds16(ga[j_] + koff_, ldsbase + (bufv) * 16384 + f_ * 512);   \
            gload_lds16(gb[j_] + koff_, ldsbase + (bufv) * 16384 + 8192 + f_ * 512); \
        }                                                                       \
    } while (0)

    STAGE(0, 0);
    __syncthreads();   // compiler emits vmcnt(0) drain before barrier

    for (int ks = 0; ks < NKS; ++ks) {
        const int buf = ks & 1;
        if (ks + 1 < NKS) STAGE(buf ^ 1, ks + 1);   // in-flight across compute
        const bf16x8* base = ldsv + buf * 2048;
#pragma unroll
        for (int kk = 0; kk < 2; ++kk) {
            bf16x8 af[4], bfr[4];
#pragma unroll
            for (int r = 0; r < 4; ++r)
                af[r] = base[((wr * 4 + r) * 2 + kk) * 64 + lane];
#pragma unroll
            for (int c = 0; c < 4; ++c)
                bfr[c] = base[1024 + ((wc * 4 + c) * 2 + kk) * 64 + lane];
#pragma unroll
            for (int r = 0; r < 4; ++r)
#pragma unroll
                for (int c = 0; c < 4; ++c)
                    acc[r][c] = __builtin_amdgcn_mfma_f32_16x16x32_bf16(af[r], bfr[c], acc[r][c], 0, 0, 0);
        }
        __syncthreads();   // drains the STAGE loads (vmcnt 0) + barrier
    }
#undef STAGE

    // tail: e = exp(2*sim); per-wave partial row/col sums -> LDS (staging LDS
    // is dead after the final K-loop barrier), cross-wave combine, then
    // exactly-once plain stores to P.
    // D-frag mapping: col = wc*64 + c*16 + l15, row = wr*64 + r*16 + lhi*4 + q
    float* rlds = reinterpret_cast<float*>(ldsbase);        // [2 (wc)][128 rows]
    float* clds = rlds + 256;                               // [2 (wr)][128 cols]
    float cs[4] = {0.f, 0.f, 0.f, 0.f};
#pragma unroll
    for (int r = 0; r < 4; ++r) {
        float rsq[4] = {0.f, 0.f, 0.f, 0.f};
#pragma unroll
        for (int c = 0; c < 4; ++c)
#pragma unroll
            for (int q = 0; q < 4; ++q) {
                float e = fexp2(KEXP2 * acc[r][c][q]);
                rsq[q] += e;
                cs[c] += e;
            }
#pragma unroll
        for (int q = 0; q < 4; ++q) {
            float v = rsq[q];
            v += __shfl_xor(v, 1, 64);
            v += __shfl_xor(v, 2, 64);
            v += __shfl_xor(v, 4, 64);
            v += __shfl_xor(v, 8, 64);
            if (l15 == 0)
                rlds[wc * 128 + wr * 64 + r * 16 + lhi * 4 + q] = v;
        }
    }
#pragma unroll
    for (int c = 0; c < 4; ++c) {
        float v = cs[c];
        v += __shfl_xor(v, 16, 64);
        v += __shfl_xor(v, 32, 64);
        if (lhi == 0)
            clds[wr * 128 + wc * 64 + c * 16 + l15] = v;
    }
    __syncthreads();
    if (tid < 128) {
        P[(size_t)tj * N + i0 + tid] = rlds[tid] + rlds[128 + tid];
    } else if (tid < 256 && !is_diag) {
        int c = tid & 127;
        P[(size_t)ti * N + j0 + c] = clds[c] + clds[128 + c];
    }
}

// Kernel 3: per row, sum the 64 partials + diag term, take log; block partial.
__global__ void k_lse(const float* __restrict__ P, const float* __restrict__ diag,
                      float* __restrict__ part, int N) {
    __shared__ float red[4];
    const int lane = threadIdx.x & 63, wv = threadIdx.x >> 6;
    const int row = blockIdx.x * 256 + threadIdx.x;
    float s = diag[row];
#pragma unroll
    for (int k = 0; k < TTILE; ++k) s += P[(size_t)k * N + row];
    float local = __logf(s);
#pragma unroll
    for (int off = 32; off >= 1; off >>= 1) local += __shfl_xor(local, off, 64);
    if (lane == 0) red[wv] = local;
    __syncthreads();
    if (threadIdx.x == 0)
        part[blockIdx.x] = red[0] + red[1] + red[2] + red[3];
}

// Kernel 4: loss = (sum part - sum pos_partial) / N
__global__ void k_final(const float* __restrict__ part, int n_part,
                        const float* __restrict__ pos_partial, int n_pos,
                        float* __restrict__ out, int N) {
    __shared__ float red[16];
    int lane = threadIdx.x & 63, wv = threadIdx.x >> 6;
    float local = 0.f;
    for (int i = threadIdx.x; i < n_part; i += 1024) local += part[i];
    for (int i = threadIdx.x; i < n_pos; i += 1024) local -= pos_partial[i];
#pragma unroll
    for (int off = 32; off >= 1; off >>= 1) local += __shfl_xor(local, off, 64);
    if (lane == 0) red[wv] = local;
    __syncthreads();
    if (threadIdx.x == 0) {
        float t = 0.f;
#pragma unroll
        for (int w = 0; w < 16; ++w) t += red[w];
        out[0] = t / (float)N;
    }
}

extern "C" void kernel_launch(void* const* d_in, const int* in_sizes, int n_in,
                              void* d_out, int out_size, void* d_ws, size_t ws_size,
                              hipStream_t stream) {
    const float* zi = (const float*)d_in[0];
    const float* zj = (const float*)d_in[1];
    const int B = in_sizes[0] / D;   // 4096
    const int N = 2 * B;             // 8192

    char* ws = (char*)d_ws;
    unsigned short* zn = (unsigned short*)ws;            // N*D bf16 = 4 MB
    float* diag = (float*)(ws + (size_t)N * D * 2);      // N f32 = 32 KB
    float* pos_partial = diag + N;                       // B/4 = 1024 f32
    float* part = pos_partial + 1024;                    // 32 f32
    float* P = part + 64;                                // 64*N f32 = 2 MB

    float* out = (float*)d_out;

    const int npb = B / 4;  // 1024 k_norm blocks == pos partials
    hipLaunchKernelGGL(k_norm, dim3(npb), dim3(256), 0, stream, zi, zj, zn, diag, pos_partial, B);
    hipLaunchKernelGGL(k_main, dim3(NBLK), dim3(256), 0, stream, zn, P, N);
    hipLaunchKernelGGL(k_lse, dim3(N / 256), dim3(256), 0, stream, P, diag, part, N);
    hipLaunchKernelGGL(k_final, dim3(1), dim3(1024), 0, stream, part, N / 256, pos_partial, npb, out, N);
}

// Round 9
// 66.081 us; speedup vs baseline: 1.3011x; 1.2720x over previous
//
#include <hip/hip_runtime.h>

typedef __attribute__((ext_vector_type(4))) float f32x4;

static constexpr int D = 256;
static constexpr float INV_T = 2.0f;                 // 1 / temperature(0.5)
static constexpr float KEXP2 = 2.8853900817779268f;  // 2*log2(e): exp(2x) = 2^(KEXP2*x)
static constexpr int BM = 128;                       // tile side
static constexpr int TTILE = 64;                     // 8192 / 128
static constexpr int NBLK = TTILE * (TTILE + 1) / 2; // 2080 upper-triangle tiles
// zn fp8 fragment-stream layout: slot s = (row>>4)*8 + (k>>5); byte =
// s*512 + lane*8 + e with lane = ((k>>3)&3)*16 + (row&15), e = k&7.
// => tile ti's 128-row panel = contiguous 32 KB at ti*32768.

__device__ inline float fexp2(float x) {
#if __has_builtin(__builtin_amdgcn_exp2f)
    return __builtin_amdgcn_exp2f(x);
#else
    return exp2f(x);
#endif
}
// Direct global->LDS DMA (16B/lane). LDS dest = wave-uniform base + lane*16.
__device__ inline void gload_lds16(const void* g, void* l) {
    typedef __attribute__((address_space(3))) unsigned int lds_u32_t;
    typedef __attribute__((address_space(1))) const unsigned int glb_u32_t;
    __builtin_amdgcn_global_load_lds((glb_u32_t*)g, (lds_u32_t*)l, 16, 0, 0);
}
// 4 floats -> 4 packed OCP e4m3 bytes (RNE, HW instr; bit-identical to MFMA's
// operand format on gfx950).
__device__ inline unsigned int cvt4_fp8(float a, float b, float c, float d) {
    int v = __builtin_amdgcn_cvt_pk_fp8_f32(a, b, 0, false);
    v = __builtin_amdgcn_cvt_pk_fp8_f32(c, d, v, true);
    return (unsigned int)v;
}

// Kernel 1: per pair i in [0,B): normalize rows i and i+B, quantize to fp8,
// scatter into fragment-stream zn layout; diag[i] = -exp(2*selfdot_fp8);
// positive-pair dot (fp8 values) -> per-block partial. No atomics.
__global__ void k_norm(const float* __restrict__ zi, const float* __restrict__ zj,
                       unsigned char* __restrict__ zn, float* __restrict__ diag,
                       float* __restrict__ pos_partial, int B) {
    __shared__ float red[4];
    const int lane = threadIdx.x & 63;
    const int wv = threadIdx.x >> 6;
    const int i = blockIdx.x * 4 + wv;       // pair index
    if (i < B) {
        float4 vi = reinterpret_cast<const float4*>(zi + (size_t)i * D)[lane];
        float4 vj = reinterpret_cast<const float4*>(zj + (size_t)i * D)[lane];
        float ssi = vi.x * vi.x + vi.y * vi.y + vi.z * vi.z + vi.w * vi.w;
        float ssj = vj.x * vj.x + vj.y * vj.y + vj.z * vj.z + vj.w * vj.w;
#pragma unroll
        for (int off = 32; off >= 1; off >>= 1) {
            ssi += __shfl_xor(ssi, off, 64);
            ssj += __shfl_xor(ssj, off, 64);
        }
        float rni = rsqrtf(ssi), rnj = rsqrtf(ssj);
        unsigned int pa = cvt4_fp8(vi.x * rni, vi.y * rni, vi.z * rni, vi.w * rni);
        unsigned int pb = cvt4_fp8(vj.x * rnj, vj.y * rnj, vj.z * rnj, vj.w * rnj);
        // decode the quantized values (exact match with what MFMA will read)
        float fa0 = __builtin_amdgcn_cvt_f32_fp8((int)pa, 0);
        float fa1 = __builtin_amdgcn_cvt_f32_fp8((int)pa, 1);
        float fa2 = __builtin_amdgcn_cvt_f32_fp8((int)pa, 2);
        float fa3 = __builtin_amdgcn_cvt_f32_fp8((int)pa, 3);
        float fb0 = __builtin_amdgcn_cvt_f32_fp8((int)pb, 0);
        float fb1 = __builtin_amdgcn_cvt_f32_fp8((int)pb, 1);
        float fb2 = __builtin_amdgcn_cvt_f32_fp8((int)pb, 2);
        float fb3 = __builtin_amdgcn_cvt_f32_fp8((int)pb, 3);
        float sdi = fa0 * fa0 + fa1 * fa1 + fa2 * fa2 + fa3 * fa3;
        float sdj = fb0 * fb0 + fb1 * fb1 + fb2 * fb2 + fb3 * fb3;
        float pd  = fa0 * fb0 + fa1 * fb1 + fa2 * fb2 + fa3 * fb3;
#pragma unroll
        for (int off = 32; off >= 1; off >>= 1) {
            sdi += __shfl_xor(sdi, off, 64);
            sdj += __shfl_xor(sdj, off, 64);
            pd  += __shfl_xor(pd, off, 64);
        }
        // scatter packed fp8 into fragment layout: lane pair (2m, 2m+1) holds
        // k = 8m..8m+7 -> one 8B slot at ((i>>4)*8 + (m>>2))*512 + ((m&3)*16 + (i&15))*8
        unsigned int qa = __shfl_xor(pa, 1, 64);
        unsigned int qb = __shfl_xor(pb, 1, 64);
        if ((lane & 1) == 0) {
            int m = lane >> 1;
            size_t base = ((size_t)(m >> 2)) * 512 + (size_t)((m & 3) * 16) * 8;
            size_t offA = ((size_t)(i >> 4)) * 4096 + base + (size_t)(i & 15) * 8;
            int ib = i + B;
            size_t offB = ((size_t)(ib >> 4)) * 4096 + base + (size_t)(ib & 15) * 8;
            *reinterpret_cast<unsigned long long*>(zn + offA) =
                ((unsigned long long)qa << 32) | pa;
            *reinterpret_cast<unsigned long long*>(zn + offB) =
                ((unsigned long long)qb << 32) | pb;
        }
        if (lane == 0) {
            diag[i]     = -fexp2(KEXP2 * sdi);
            diag[i + B] = -fexp2(KEXP2 * sdj);
            red[wv] = pd;
        }
    } else if (lane == 0) {
        red[wv] = 0.f;
    }
    __syncthreads();
    if (threadIdx.x == 0)
        pos_partial[blockIdx.x] = 2.0f * INV_T * (red[0] + red[1] + red[2] + red[3]);
}

// Kernel 2: upper-triangle 128x128 sim tiles, fp8 MFMA. Full K=256 for both
// panels resident in LDS (32 KB + 32 KB, 2 blocks/CU): ONE contiguous stage
// (global_load_lds from the fragment-stream layout), ONE barrier, then
// free-run compute with no further syncs (R8's per-step vmcnt(0) barriers
// each ate a worst-case HBM latency). Tail = R8's proven cross-wave combine
// + exactly-once P stores.
__global__ __launch_bounds__(256, 2)
void k_main(const unsigned char* __restrict__ zn, float* __restrict__ P, int N) {
    __shared__ __align__(16) unsigned char lds[65536];
    const int tid = threadIdx.x;
    const int lane = tid & 63, wv = tid >> 6;
    const int l15 = lane & 15, lhi = lane >> 4;
    const int wr = wv >> 1, wc = wv & 1;         // wave grid 2 x 2

    // decode upper-triangle tile (ti <= tj)
    int ti = 0, rem = blockIdx.x;
    while (rem >= TTILE - ti) { rem -= TTILE - ti; ++ti; }
    const int tj = ti + rem;
    const bool is_diag = (ti == tj);
    const int i0 = ti * BM, j0 = tj * BM;

    // stage both 32 KB panels (contiguous in the fragment-stream layout)
    const unsigned char* srcA = zn + (size_t)ti * 32768;
    const unsigned char* srcB = zn + (size_t)tj * 32768;
#pragma unroll
    for (int j = 0; j < 8; ++j) {
        int cu = (wv * 64 + 256 * j) * 16;       // wave-uniform byte offset
        gload_lds16(srcA + cu + lane * 16, lds + cu);
        gload_lds16(srcB + cu + lane * 16, lds + 32768 + cu);
    }
    __syncthreads();   // single drain for the whole block

    f32x4 acc[4][4];
#pragma unroll
    for (int r = 0; r < 4; ++r)
#pragma unroll
        for (int c = 0; c < 4; ++c) acc[r][c] = (f32x4){0.f, 0.f, 0.f, 0.f};

#pragma unroll
    for (int kk = 0; kk < 8; ++kk) {
        long long af[4], bf[4];
#pragma unroll
        for (int r = 0; r < 4; ++r)
            af[r] = *reinterpret_cast<const long long*>(
                lds + ((wr * 4 + r) * 8 + kk) * 512 + lane * 8);
#pragma unroll
        for (int c = 0; c < 4; ++c)
            bf[c] = *reinterpret_cast<const long long*>(
                lds + 32768 + ((wc * 4 + c) * 8 + kk) * 512 + lane * 8);
#pragma unroll
        for (int r = 0; r < 4; ++r)
#pragma unroll
            for (int c = 0; c < 4; ++c)
                acc[r][c] = __builtin_amdgcn_mfma_f32_16x16x32_fp8_fp8(
                    af[r], bf[c], acc[r][c], 0, 0, 0);
    }
    __syncthreads();   // all LDS reads done before tail reuses the buffer

    // tail: e = exp(2*sim); per-wave row/col partials -> LDS, cross-wave
    // combine, exactly-once plain stores to P.
    // D-frag mapping: col = wc*64 + c*16 + l15, row = wr*64 + r*16 + lhi*4 + q
    float* rlds = reinterpret_cast<float*>(lds);        // [2 (wc)][128 rows]
    float* clds = rlds + 256;                           // [2 (wr)][128 cols]
    float cs[4] = {0.f, 0.f, 0.f, 0.f};
#pragma unroll
    for (int r = 0; r < 4; ++r) {
        float rsq[4] = {0.f, 0.f, 0.f, 0.f};
#pragma unroll
        for (int c = 0; c < 4; ++c)
#pragma unroll
            for (int q = 0; q < 4; ++q) {
                float e = fexp2(KEXP2 * acc[r][c][q]);
                rsq[q] += e;
                cs[c] += e;
            }
#pragma unroll
        for (int q = 0; q < 4; ++q) {
            float v = rsq[q];
            v += __shfl_xor(v, 1, 64);
            v += __shfl_xor(v, 2, 64);
            v += __shfl_xor(v, 4, 64);
            v += __shfl_xor(v, 8, 64);
            if (l15 == 0)
                rlds[wc * 128 + wr * 64 + r * 16 + lhi * 4 + q] = v;
        }
    }
#pragma unroll
    for (int c = 0; c < 4; ++c) {
        float v = cs[c];
        v += __shfl_xor(v, 16, 64);
        v += __shfl_xor(v, 32, 64);
        if (lhi == 0)
            clds[wr * 128 + wc * 64 + c * 16 + l15] = v;
    }
    __syncthreads();
    if (tid < 128) {
        P[(size_t)tj * N + i0 + tid] = rlds[tid] + rlds[128 + tid];
    } else if (tid < 256 && !is_diag) {
        int c = tid & 127;
        P[(size_t)ti * N + j0 + c] = clds[c] + clds[128 + c];
    }
}

// Kernel 3: per row, sum the 64 partials + diag term, take log; block partial.
__global__ void k_lse(const float* __restrict__ P, const float* __restrict__ diag,
                      float* __restrict__ part, int N) {
    __shared__ float red[4];
    const int lane = threadIdx.x & 63, wv = threadIdx.x >> 6;
    const int row = blockIdx.x * 256 + threadIdx.x;
    float s = diag[row];
#pragma unroll
    for (int k = 0; k < TTILE; ++k) s += P[(size_t)k * N + row];
    float local = __logf(s);
#pragma unroll
    for (int off = 32; off >= 1; off >>= 1) local += __shfl_xor(local, off, 64);
    if (lane == 0) red[wv] = local;
    __syncthreads();
    if (threadIdx.x == 0)
        part[blockIdx.x] = red[0] + red[1] + red[2] + red[3];
}

// Kernel 4: loss = (sum part - sum pos_partial) / N
__global__ void k_final(const float* __restrict__ part, int n_part,
                        const float* __restrict__ pos_partial, int n_pos,
                        float* __restrict__ out, int N) {
    __shared__ float red[16];
    int lane = threadIdx.x & 63, wv = threadIdx.x >> 6;
    float local = 0.f;
    for (int i = threadIdx.x; i < n_part; i += 1024) local += part[i];
    for (int i = threadIdx.x; i < n_pos; i += 1024) local -= pos_partial[i];
#pragma unroll
    for (int off = 32; off >= 1; off >>= 1) local += __shfl_xor(local, off, 64);
    if (lane == 0) red[wv] = local;
    __syncthreads();
    if (threadIdx.x == 0) {
        float t = 0.f;
#pragma unroll
        for (int w = 0; w < 16; ++w) t += red[w];
        out[0] = t / (float)N;
    }
}

extern "C" void kernel_launch(void* const* d_in, const int* in_sizes, int n_in,
                              void* d_out, int out_size, void* d_ws, size_t ws_size,
                              hipStream_t stream) {
    const float* zi = (const float*)d_in[0];
    const float* zj = (const float*)d_in[1];
    const int B = in_sizes[0] / D;   // 4096
    const int N = 2 * B;             // 8192

    char* ws = (char*)d_ws;
    unsigned char* zn = (unsigned char*)ws;              // N*D fp8 = 2 MB
    float* diag = (float*)(ws + (size_t)N * D);          // N f32 = 32 KB
    float* pos_partial = diag + N;                       // B/4 = 1024 f32
    float* part = pos_partial + 1024;                    // 32 f32
    float* P = part + 64;                                // 64*N f32 = 2 MB

    float* out = (float*)d_out;

    const int npb = B / 4;  // 1024 k_norm blocks == pos partials
    hipLaunchKernelGGL(k_norm, dim3(npb), dim3(256), 0, stream, zi, zj, zn, diag, pos_partial, B);
    hipLaunchKernelGGL(k_main, dim3(NBLK), dim3(256), 0, stream, zn, P, N);
    hipLaunchKernelGGL(k_lse, dim3(N / 256), dim3(256), 0, stream, P, diag, part, N);
    hipLaunchKernelGGL(k_final, dim3(1), dim3(1024), 0, stream, part, N / 256, pos_partial, npb, out, N);
}